// Round 11
// baseline (254.122 us; speedup 1.0000x reference)
//
#include <hip/hip_runtime.h>
#include <math.h>

// Problem constants: T=131072, D_IN=1024, NE=64, top_k=2
constexpr int T_TOKENS = 131072;
constexpr int D        = 1024;
constexpr int NSTEPS   = 32;       // K steps of 32
constexpr float EPS_GAP = 1e-3f;   // flag threshold (bf16-split err ~2e-5 RMS)

typedef __attribute__((ext_vector_type(8))) short bf16x8;
typedef __attribute__((ext_vector_type(4))) float f32x4;

__device__ __forceinline__ short bf16_rn(float f) {
    unsigned u = __builtin_bit_cast(unsigned, f);
    return (short)((u + 0x7FFFu + ((u >> 16) & 1u)) >> 16);
}
__device__ __forceinline__ float bf16_f(short s) {
    unsigned u = ((unsigned)(unsigned short)s) << 16;
    return __builtin_bit_cast(float, u);
}
// split 8 fp32 into two bf16 planes: f ~= p0 + p1
__device__ __forceinline__ void split2(const float4 lo, const float4 hi,
                                       bf16x8& p0, bf16x8& p1) {
    const float f[8] = {lo.x, lo.y, lo.z, lo.w, hi.x, hi.y, hi.z, hi.w};
#pragma unroll
    for (int j = 0; j < 8; ++j) {
        const short h = bf16_rn(f[j]);
        p0[j] = h;
        p1[j] = bf16_rn(f[j] - bf16_f(h));
    }
}

// ---- Kernel 0: pre-split W into fragment-layout bf16 planes (256 KB) ------
// frag[((s*4 + c)*2 + p)*64 + l] = plane_p( W[c*16 + (l&15)][s*32 + (l>>4)*8 .. +8] )
__global__ void prep_w(const float* __restrict__ W, bf16x8* __restrict__ wpl) {
    const int s = blockIdx.x;          // 0..31
    const int c = threadIdx.x >> 6;    // 0..3
    const int l = threadIdx.x & 63;
    const int e  = c * 16 + (l & 15);
    const int k0 = s * 32 + (l >> 4) * 8;
    const float4 lo = *(const float4*)(W + (long)e * D + k0);
    const float4 hi = *(const float4*)(W + (long)e * D + k0 + 4);
    bf16x8 p0, p1; split2(lo, hi, p0, p1);
    const int base = ((s * 4 + c) * 2) * 64 + l;
    wpl[base]      = p0;
    wpl[base + 64] = p1;
}

// ---- Kernel 1: bf16-split MFMA router, no LDS, no barriers ----------------
// 1024 blocks x 256 thr (4 waves); wave = 32 tokens (2 tiles) x 64 experts.
// A: global->reg, split in-reg, 1-step prefetch. W: precomputed frags,
// 8 coalesced 16B-lane loads/step (same 8KB read by all waves -> L1-hot).
// 3 MFMA passes: x0*w0 + x1*w0 + x0*w1.
__global__ __launch_bounds__(256, 4)
void router_mfma(const float* __restrict__ x, const bf16x8* __restrict__ wpl,
                 float* __restrict__ out, unsigned* __restrict__ wcnt,
                 unsigned* __restrict__ wlist, unsigned cap)
{
    const int tid = threadIdx.x;
    const int wv  = tid >> 6;
    const int l   = tid & 63;
    const int lg  = l >> 4;       // k-octet
    const int lr  = l & 15;       // row/col within 16
    const long t0 = (long)blockIdx.x * 128 + wv * 32;

    f32x4 acc[2][4];
#pragma unroll
    for (int a = 0; a < 2; ++a)
#pragma unroll
        for (int c = 0; c < 4; ++c) acc[a][c] = f32x4{0.f, 0.f, 0.f, 0.f};

    const float* xr0 = x + (t0 + lr) * (long)D + lg * 8;
    const float* xr1 = xr0 + 16 * (long)D;

    float4 af[2][2];
    bf16x8 afr[2][2], bfr[4][2];

    // ---- prologue: A(0), W(0); split A(0); issue A(1) ----
    af[0][0] = *(const float4*)(xr0);  af[0][1] = *(const float4*)(xr0 + 4);
    af[1][0] = *(const float4*)(xr1);  af[1][1] = *(const float4*)(xr1 + 4);
#pragma unroll
    for (int c = 0; c < 4; ++c) {
        bfr[c][0] = wpl[(c * 2 + 0) * 64 + l];
        bfr[c][1] = wpl[(c * 2 + 1) * 64 + l];
    }
    split2(af[0][0], af[0][1], afr[0][0], afr[0][1]);
    split2(af[1][0], af[1][1], afr[1][0], afr[1][1]);
    af[0][0] = *(const float4*)(xr0 + 32); af[0][1] = *(const float4*)(xr0 + 36);
    af[1][0] = *(const float4*)(xr1 + 32); af[1][1] = *(const float4*)(xr1 + 36);

#pragma unroll 1
    for (int s = 0; s < NSTEPS - 1; ++s) {
        // MFMA(s): afr x bfr (all register-resident)
#pragma unroll
        for (int c = 0; c < 4; ++c)
#pragma unroll
            for (int a = 0; a < 2; ++a) {
                acc[a][c] = __builtin_amdgcn_mfma_f32_16x16x32_bf16(afr[a][0], bfr[c][0], acc[a][c], 0, 0, 0);
                acc[a][c] = __builtin_amdgcn_mfma_f32_16x16x32_bf16(afr[a][1], bfr[c][0], acc[a][c], 0, 0, 0);
                acc[a][c] = __builtin_amdgcn_mfma_f32_16x16x32_bf16(afr[a][0], bfr[c][1], acc[a][c], 0, 0, 0);
            }
        // load W(s+1) (L1-hot; covered by the split below + next MFMA)
        {
            const int wb = (s + 1) * 8 * 64;
#pragma unroll
            for (int c = 0; c < 4; ++c) {
                bfr[c][0] = wpl[wb + (c * 2 + 0) * 64 + l];
                bfr[c][1] = wpl[wb + (c * 2 + 1) * 64 + l];
            }
        }
        // split A(s+1) (loaded one full step ago)
        split2(af[0][0], af[0][1], afr[0][0], afr[0][1]);
        split2(af[1][0], af[1][1], afr[1][0], afr[1][1]);
        // issue A(s+2)
        if (s + 2 < NSTEPS) {
            const int o = (s + 2) * 32;
            af[0][0] = *(const float4*)(xr0 + o); af[0][1] = *(const float4*)(xr0 + o + 4);
            af[1][0] = *(const float4*)(xr1 + o); af[1][1] = *(const float4*)(xr1 + o + 4);
        }
    }
    // final step's MFMA
#pragma unroll
    for (int c = 0; c < 4; ++c)
#pragma unroll
        for (int a = 0; a < 2; ++a) {
            acc[a][c] = __builtin_amdgcn_mfma_f32_16x16x32_bf16(afr[a][0], bfr[c][0], acc[a][c], 0, 0, 0);
            acc[a][c] = __builtin_amdgcn_mfma_f32_16x16x32_bf16(afr[a][1], bfr[c][0], acc[a][c], 0, 0, 0);
            acc[a][c] = __builtin_amdgcn_mfma_f32_16x16x32_bf16(afr[a][0], bfr[c][1], acc[a][c], 0, 0, 0);
        }

    // ---- epilogue: top-3 per token, provisional write + gap-flag ----
    // C/D: col = lane&15 (expert within ctile), row = (lane>>4)*4 + reg (token)
#pragma unroll
    for (int a = 0; a < 2; ++a)
#pragma unroll
    for (int r = 0; r < 4; ++r) {
        float v1 = acc[a][0][r]; int i1 = lr;
        float v2 = -INFINITY;    int i2 = 1 << 20;
        float v3 = -INFINITY;
#pragma unroll
        for (int c = 1; c < 4; ++c) {
            const float v = acc[a][c][r]; const int e = lr + 16 * c;
            if (v > v1)      { v3 = v2; v2 = v1; i2 = i1; v1 = v; i1 = e; }
            else if (v > v2) { v3 = v2; v2 = v;  i2 = e; }
            else if (v > v3) { v3 = v; }
        }
#pragma unroll
        for (int m = 8; m >= 1; m >>= 1) {
            const float ov1 = __shfl_xor(v1, m);
            const int   oi1 = __shfl_xor(i1, m);
            const float ov2 = __shfl_xor(v2, m);
            const int   oi2 = __shfl_xor(i2, m);
            const float ov3 = __shfl_xor(v3, m);
            const bool tv = v1 >= ov1;
            const float x1 = tv ? v1 : ov1, x2 = tv ? v2 : ov2, x3 = tv ? v3 : ov3;
            const float y1 = tv ? ov1 : v1, y2 = tv ? ov2 : v2;
            const float nv3 = (x2 >= y1) ? fmaxf(x3, y1) : fmaxf(x2, y2);
            (void)x1;
            const bool aw = (ov1 > v1) || (ov1 == v1 && oi1 < i1);
            const float nv1 = aw ? ov1 : v1; const int ni1 = aw ? oi1 : i1;
            const float c1v = aw ? v1  : ov1; const int c1i = aw ? i1  : oi1;
            const float c2v = aw ? ov2 : v2;  const int c2i = aw ? oi2 : i2;
            const bool bw = (c1v > c2v) || (c1v == c2v && c1i < c2i);
            v1 = nv1; i1 = ni1;
            v2 = bw ? c1v : c2v; i2 = bw ? c1i : c2i;
            v3 = nv3;
        }
        if (lr == 0) {
            const long t = t0 + a * 16 + lg * 4 + r;
            const float e  = expf(v2 - v1);
            const float dn = 1.0f + e;
            out[t * 2 + 0] = (float)i1;
            out[t * 2 + 1] = (float)i2;
            out[(long)T_TOKENS * 2 + t * 2 + 0] = 1.0f / dn;
            out[(long)T_TOKENS * 2 + t * 2 + 1] = e / dn;
            if (v1 - v2 < EPS_GAP || v2 - v3 < EPS_GAP) {
                const unsigned p = atomicAdd(wcnt, 1u);
                if (p < cap) wlist[p] = (unsigned)t;
            }
        }
    }
}

// ---- Kernel 2: exact-chain fixup, 4 waves/token (one per OpenBLAS panel) --
// Exact OpenBLAS-SKYLAKEX chain (verified R7): panels 320/320/192/192,
// ascending-k fp32 FMA chain per panel, sequential rounded folds.
__global__ __launch_bounds__(256)
void router_fixup(const float* __restrict__ x, const float* __restrict__ W,
                  float* __restrict__ out, const unsigned* __restrict__ wcnt,
                  const unsigned* __restrict__ wlist, unsigned cap)
{
    __shared__ float ps[4][64];
    unsigned cnt = wcnt[0]; if (cnt > cap) cnt = cap;
    const int wv = threadIdx.x >> 6;   // panel id
    const int l  = threadIdx.x & 63;   // expert
    const int kb = (wv == 0) ? 0 : (wv == 1) ? 320 : (wv == 2) ? 640 : 832;
    const int ke = (wv == 0) ? 320 : (wv == 1) ? 640 : (wv == 2) ? 832 : 1024;

    for (unsigned it = blockIdx.x; it < cnt; it += gridDim.x) {
        const long t = (long)wlist[it];
        const float* xr = x + t * (long)D;
        const float* wr = W + (long)l * D;
        float accP = 0.f;
#pragma unroll 4
        for (int k = kb; k < ke; k += 4) {
            const float4 xv = *(const float4*)(xr + k);
            const float4 wvv = *(const float4*)(wr + k);
            accP = fmaf(xv.x, wvv.x, accP);
            accP = fmaf(xv.y, wvv.y, accP);
            accP = fmaf(xv.z, wvv.z, accP);
            accP = fmaf(xv.w, wvv.w, accP);
        }
        ps[wv][l] = accP;
        __syncthreads();
        if (wv == 0) {
            const float accT = __fadd_rn(__fadd_rn(__fadd_rn(ps[0][l], ps[1][l]), ps[2][l]), ps[3][l]);
            float v1 = accT; int i1 = l;
            float v2 = -INFINITY; int i2 = 1 << 20;
#pragma unroll
            for (int m = 32; m >= 1; m >>= 1) {
                const float ov1 = __shfl_xor(v1, m);
                const int   oi1 = __shfl_xor(i1, m);
                const float ov2 = __shfl_xor(v2, m);
                const int   oi2 = __shfl_xor(i2, m);
                const bool aw = (ov1 > v1) || (ov1 == v1 && oi1 < i1);
                const float nv1 = aw ? ov1 : v1; const int ni1 = aw ? oi1 : i1;
                const float c1v = aw ? v1  : ov1; const int c1i = aw ? i1  : oi1;
                const float c2v = aw ? ov2 : v2;  const int c2i = aw ? oi2 : i2;
                const bool bw = (c1v > c2v) || (c1v == c2v && c1i < c2i);
                v1 = nv1; i1 = ni1;
                v2 = bw ? c1v : c2v; i2 = bw ? c1i : c2i;
            }
            if (l == 0) {
                const float e  = expf(v2 - v1);
                const float dn = 1.0f + e;
                out[t * 2 + 0] = (float)i1;
                out[t * 2 + 1] = (float)i2;
                out[(long)T_TOKENS * 2 + t * 2 + 0] = 1.0f / dn;
                out[(long)T_TOKENS * 2 + t * 2 + 1] = e / dn;
            }
        }
        __syncthreads();
    }
}

extern "C" void kernel_launch(void* const* d_in, const int* in_sizes, int n_in,
                              void* d_out, int out_size, void* d_ws, size_t ws_size,
                              hipStream_t stream) {
    const float* x = (const float*)d_in[0];
    const float* W = (const float*)d_in[1];
    float* out = (float*)d_out;

    // workspace layout: [0,64) wcnt | [1024, 1024+256K) W frag planes | wlist
    unsigned* wcnt  = (unsigned*)d_ws;
    bf16x8*   wpl   = (bf16x8*)((char*)d_ws + 1024);
    unsigned* wlist = (unsigned*)((char*)d_ws + 1024 + 262144);
    size_t rem = (ws_size - 1024 - 262144) / 4;
    unsigned cap = (unsigned)(rem > (1u << 22) ? (1u << 22) : rem);

    hipMemsetAsync(d_ws, 0, 64, stream);
    prep_w<<<dim3(32), dim3(256), 0, stream>>>(W, wpl);
    router_mfma<<<dim3(T_TOKENS / 128), dim3(256), 0, stream>>>(x, wpl, out, wcnt, wlist, cap);
    router_fixup<<<dim3(1024), dim3(256), 0, stream>>>(x, W, out, wcnt, wlist, cap);
}

// Round 13
// 252.881 us; speedup vs baseline: 1.0049x; 1.0049x over previous
//
#include <hip/hip_runtime.h>
#include <math.h>

// Problem constants: T=131072, D_IN=1024, NE=64, top_k=2
constexpr int T_TOKENS = 131072;
constexpr int D        = 1024;
constexpr int KSTEP    = 128;          // K per LDS stage step (512B/row contiguous)
constexpr int NSTEP    = D / KSTEP;    // 8
constexpr float EPS_GAP = 1e-3f;       // flag threshold (bf16-split err ~2e-5 RMS)

typedef __attribute__((ext_vector_type(8))) short bf16x8;
typedef __attribute__((ext_vector_type(4))) float f32x4;

__device__ __forceinline__ short bf16_rn(float f) {
    unsigned u = __builtin_bit_cast(unsigned, f);
    return (short)((u + 0x7FFFu + ((u >> 16) & 1u)) >> 16);
}
__device__ __forceinline__ float bf16_f(short s) {
    unsigned u = ((unsigned)(unsigned short)s) << 16;
    return __builtin_bit_cast(float, u);
}
// split 8 fp32 into two bf16 planes: f ~= p0 + p1
__device__ __forceinline__ void split2(const float4 lo, const float4 hi,
                                       bf16x8& p0, bf16x8& p1) {
    const float f[8] = {lo.x, lo.y, lo.z, lo.w, hi.x, hi.y, hi.z, hi.w};
#pragma unroll
    for (int j = 0; j < 8; ++j) {
        const short h = bf16_rn(f[j]);
        p0[j] = h;
        p1[j] = bf16_rn(f[j] - bf16_f(h));
    }
}

// ---- Kernel 0: pre-split W into fragment-layout bf16 planes (256 KB) ------
// wpl[g*512 + (c*2+p)*64 + l] = plane_p( W[c*16 + (l&15)][g*32 + (l>>4)*8 .. +8] )
__global__ void prep_w(const float* __restrict__ W, bf16x8* __restrict__ wpl) {
    const int g = blockIdx.x;          // 0..31 (K window of 32)
    const int c = threadIdx.x >> 6;    // 0..3
    const int l = threadIdx.x & 63;
    const int e  = c * 16 + (l & 15);
    const int k0 = g * 32 + (l >> 4) * 8;
    const float4 lo = *(const float4*)(W + (long)e * D + k0);
    const float4 hi = *(const float4*)(W + (long)e * D + k0 + 4);
    bf16x8 p0, p1; split2(lo, hi, p0, p1);
    const int base = ((g * 4 + c) * 2) * 64 + l;
    wpl[base]      = p0;
    wpl[base + 64] = p1;
}

// ---- Kernel 1: bf16-split MFMA router, contiguous x via global_load_lds ----
// 2048 blocks x 256 thr (4 waves); wave = 16 tokens x 64 experts.
// x: 512B/row runs staged direct-to-LDS (double-buffered 2x32KB), source
// pre-swizzled (q ^ ((row&7)<<4)) so swizzled ds_read_b128 is spread.
// W: precomputed frag planes, register-loaded per 32-k substep (L1-hot).
// 3 MFMA passes: x0*w0 + x1*w0 + x0*w1.
__global__ __launch_bounds__(256, 2)
void router_mfma(const float* __restrict__ x, const bf16x8* __restrict__ wpl,
                 float* __restrict__ out, unsigned* __restrict__ wcnt,
                 unsigned* __restrict__ wlist, unsigned cap)
{
    __shared__ float Xs[2][64 * KSTEP];   // 2 x 32 KB

    const int tid = threadIdx.x;
    const int wv  = tid >> 6;
    const int l   = tid & 63;
    const int lg  = l >> 4;       // k-octet
    const int lr  = l & 15;       // A row within tile / expert within ctile
    const long tblk = (long)blockIdx.x * 64;
    const int r   = 16 * wv + lr;            // this lane's A row in block
    const int swz = (lr & 7) << 4;           // 16B-granule XOR swizzle

    f32x4 acc[4];
#pragma unroll
    for (int c = 0; c < 4; ++c) acc[c] = f32x4{0.f, 0.f, 0.f, 0.f};

    // staging lane geometry: inst i covers rows 16wv+2i, 16wv+2i+1 (wave-private)
    const int sq = (l & 31) * 16;            // byte col within row segment
    const char* xb = (const char*)x;

#define STAGE(S, BUF)                                                          \
    {                                                                          \
        _Pragma("unroll")                                                      \
        for (int i = 0; i < 8; ++i) {                                          \
            const int rr = 16 * wv + 2 * i + (l >> 5);                         \
            const char* src = xb + (tblk + rr) * (long)(D * 4) + (S) * 512     \
                              + (sq ^ ((rr & 7) << 4));                        \
            char* dst = (char*)&Xs[BUF][0] + (16 * wv + 2 * i) * 512;          \
            __builtin_amdgcn_global_load_lds(                                  \
                (const __attribute__((address_space(1))) void*)src,            \
                (__attribute__((address_space(3))) void*)dst, 16, 0, 0);       \
        }                                                                      \
    }

    STAGE(0, 0);
    __syncthreads();   // drains vmcnt -> buf0 ready

#pragma unroll 1
    for (int s = 0; s < NSTEP; ++s) {
        const int cur = s & 1;
        if (s + 1 < NSTEP) {
            if (cur) STAGE(s + 1, 0) else STAGE(s + 1, 1)
        }

        const char* arow = (const char*)&Xs[cur][0] + r * 512;
#pragma unroll
        for (int sub = 0; sub < 4; ++sub) {
            const int g = s * 4 + sub;
            bf16x8 b[4][2];
#pragma unroll
            for (int c = 0; c < 4; ++c) {
                b[c][0] = wpl[(size_t)g * 512 + (c * 2 + 0) * 64 + l];
                b[c][1] = wpl[(size_t)g * 512 + (c * 2 + 1) * 64 + l];
            }
            const int c0 = sub * 128 + lg * 32;
            const float4 lo = *(const float4*)(arow + (c0 ^ swz));
            const float4 hi = *(const float4*)(arow + ((c0 + 16) ^ swz));
            bf16x8 a0, a1;
            split2(lo, hi, a0, a1);
#pragma unroll
            for (int c = 0; c < 4; ++c) {
                acc[c] = __builtin_amdgcn_mfma_f32_16x16x32_bf16(a0, b[c][0], acc[c], 0, 0, 0);
                acc[c] = __builtin_amdgcn_mfma_f32_16x16x32_bf16(a1, b[c][0], acc[c], 0, 0, 0);
                acc[c] = __builtin_amdgcn_mfma_f32_16x16x32_bf16(a0, b[c][1], acc[c], 0, 0, 0);
            }
        }
        __syncthreads();   // drains STAGE(s+1); buffers are wave-private otherwise
    }
#undef STAGE

    // ---- epilogue: top-3 per token, provisional write + gap-flag ----
    // C/D: col = lane&15 (expert in ctile), row = (lane>>4)*4 + reg (token)
#pragma unroll
    for (int rg = 0; rg < 4; ++rg) {
        float v1 = acc[0][rg]; int i1 = lr;
        float v2 = -INFINITY;  int i2 = 1 << 20;
        float v3 = -INFINITY;
#pragma unroll
        for (int c = 1; c < 4; ++c) {
            const float v = acc[c][rg]; const int e = lr + 16 * c;
            if (v > v1)      { v3 = v2; v2 = v1; i2 = i1; v1 = v; i1 = e; }
            else if (v > v2) { v3 = v2; v2 = v;  i2 = e; }
            else if (v > v3) { v3 = v; }
        }
#pragma unroll
        for (int m = 8; m >= 1; m >>= 1) {
            const float ov1 = __shfl_xor(v1, m);
            const int   oi1 = __shfl_xor(i1, m);
            const float ov2 = __shfl_xor(v2, m);
            const int   oi2 = __shfl_xor(i2, m);
            const float ov3 = __shfl_xor(v3, m);
            const bool tv = v1 >= ov1;
            const float x2 = tv ? v2 : ov2, x3 = tv ? v3 : ov3;
            const float y1 = tv ? ov1 : v1, y2 = tv ? ov2 : v2;
            const float nv3 = (x2 >= y1) ? fmaxf(x3, y1) : fmaxf(x2, y2);
            const bool aw = (ov1 > v1) || (ov1 == v1 && oi1 < i1);
            const float nv1 = aw ? ov1 : v1; const int ni1 = aw ? oi1 : i1;
            const float c1v = aw ? v1  : ov1; const int c1i = aw ? i1  : oi1;
            const float c2v = aw ? ov2 : v2;  const int c2i = aw ? oi2 : i2;
            const bool bw = (c1v > c2v) || (c1v == c2v && c1i < c2i);
            v1 = nv1; i1 = ni1;
            v2 = bw ? c1v : c2v; i2 = bw ? c1i : c2i;
            v3 = nv3;
        }
        if (lr == 0) {
            const long t = tblk + 16 * wv + lg * 4 + rg;
            const float e  = expf(v2 - v1);
            const float dn = 1.0f + e;
            out[t * 2 + 0] = (float)i1;
            out[t * 2 + 1] = (float)i2;
            out[(long)T_TOKENS * 2 + t * 2 + 0] = 1.0f / dn;
            out[(long)T_TOKENS * 2 + t * 2 + 1] = e / dn;
            if (v1 - v2 < EPS_GAP || v2 - v3 < EPS_GAP) {
                const unsigned p = atomicAdd(wcnt, 1u);
                if (p < cap) wlist[p] = (unsigned)t;
            }
        }
    }
}

// ---- Kernel 2: exact-chain fixup, 4 waves/token (one per OpenBLAS panel) --
// Exact OpenBLAS-SKYLAKEX chain (verified R7/R10/R11): panels 320/320/192/192,
// ascending-k fp32 FMA chain per panel, sequential rounded folds.
__global__ __launch_bounds__(256)
void router_fixup(const float* __restrict__ x, const float* __restrict__ W,
                  float* __restrict__ out, const unsigned* __restrict__ wcnt,
                  const unsigned* __restrict__ wlist, unsigned cap)
{
    __shared__ float ps[4][64];
    unsigned cnt = wcnt[0]; if (cnt > cap) cnt = cap;
    const int wv = threadIdx.x >> 6;   // panel id
    const int l  = threadIdx.x & 63;   // expert
    const int kb = (wv == 0) ? 0 : (wv == 1) ? 320 : (wv == 2) ? 640 : 832;
    const int ke = (wv == 0) ? 320 : (wv == 1) ? 640 : (wv == 2) ? 832 : 1024;

    for (unsigned it = blockIdx.x; it < cnt; it += gridDim.x) {
        const long t = (long)wlist[it];
        const float* xr = x + t * (long)D;
        const float* wr = W + (long)l * D;
        float accP = 0.f;
#pragma unroll 4
        for (int k = kb; k < ke; k += 4) {
            const float4 xv = *(const float4*)(xr + k);
            const float4 wvv = *(const float4*)(wr + k);
            accP = fmaf(xv.x, wvv.x, accP);
            accP = fmaf(xv.y, wvv.y, accP);
            accP = fmaf(xv.z, wvv.z, accP);
            accP = fmaf(xv.w, wvv.w, accP);
        }
        ps[wv][l] = accP;
        __syncthreads();
        if (wv == 0) {
            const float accT = __fadd_rn(__fadd_rn(__fadd_rn(ps[0][l], ps[1][l]), ps[2][l]), ps[3][l]);
            float v1 = accT; int i1 = l;
            float v2 = -INFINITY; int i2 = 1 << 20;
#pragma unroll
            for (int m = 32; m >= 1; m >>= 1) {
                const float ov1 = __shfl_xor(v1, m);
                const int   oi1 = __shfl_xor(i1, m);
                const float ov2 = __shfl_xor(v2, m);
                const int   oi2 = __shfl_xor(i2, m);
                const bool aw = (ov1 > v1) || (ov1 == v1 && oi1 < i1);
                const float nv1 = aw ? ov1 : v1; const int ni1 = aw ? oi1 : i1;
                const float c1v = aw ? v1  : ov1; const int c1i = aw ? i1  : oi1;
                const float c2v = aw ? ov2 : v2;  const int c2i = aw ? oi2 : i2;
                const bool bw = (c1v > c2v) || (c1v == c2v && c1i < c2i);
                v1 = nv1; i1 = ni1;
                v2 = bw ? c1v : c2v; i2 = bw ? c1i : c2i;
            }
            if (l == 0) {
                const float e  = expf(v2 - v1);
                const float dn = 1.0f + e;
                out[t * 2 + 0] = (float)i1;
                out[t * 2 + 1] = (float)i2;
                out[(long)T_TOKENS * 2 + t * 2 + 0] = 1.0f / dn;
                out[(long)T_TOKENS * 2 + t * 2 + 1] = e / dn;
            }
        }
        __syncthreads();
    }
}

extern "C" void kernel_launch(void* const* d_in, const int* in_sizes, int n_in,
                              void* d_out, int out_size, void* d_ws, size_t ws_size,
                              hipStream_t stream) {
    const float* x = (const float*)d_in[0];
    const float* W = (const float*)d_in[1];
    float* out = (float*)d_out;

    // workspace layout: [0,64) wcnt | [1024, 1024+256K) W frag planes | wlist
    unsigned* wcnt  = (unsigned*)d_ws;
    bf16x8*   wpl   = (bf16x8*)((char*)d_ws + 1024);
    unsigned* wlist = (unsigned*)((char*)d_ws + 1024 + 262144);
    size_t rem = (ws_size - 1024 - 262144) / 4;
    unsigned cap = (unsigned)(rem > (1u << 22) ? (1u << 22) : rem);

    (void)hipMemsetAsync(d_ws, 0, 64, stream);
    prep_w<<<dim3(32), dim3(256), 0, stream>>>(W, wpl);
    router_mfma<<<dim3(T_TOKENS / 64), dim3(256), 0, stream>>>(x, wpl, out, wcnt, wlist, cap);
    router_fixup<<<dim3(512), dim3(256), 0, stream>>>(x, W, out, wcnt, wlist, cap);
}

// Round 14
// 209.517 us; speedup vs baseline: 1.2129x; 1.2070x over previous
//
#include <hip/hip_runtime.h>
#include <math.h>

// Problem constants: T=131072, D_IN=1024, NE=64, top_k=2
constexpr int T_TOKENS = 131072;
constexpr int D        = 1024;
constexpr int NSTEPS   = 32;       // K steps of 32
constexpr float EPS_GAP = 1e-3f;   // flag threshold (bf16-split err ~1e-5 RMS)

typedef __attribute__((ext_vector_type(8))) short bf16x8;
typedef __attribute__((ext_vector_type(4))) float f32x4;

__device__ __forceinline__ short bf16_rn(float f) {
    unsigned u = __builtin_bit_cast(unsigned, f);
    return (short)((u + 0x7FFFu + ((u >> 16) & 1u)) >> 16);
}
__device__ __forceinline__ float bf16_f(short s) {
    unsigned u = ((unsigned)(unsigned short)s) << 16;
    return __builtin_bit_cast(float, u);
}
// split 8 fp32 into two bf16 planes: f ~= p0 + p1
__device__ __forceinline__ void split2(const float4 lo, const float4 hi,
                                       bf16x8& p0, bf16x8& p1) {
    const float f[8] = {lo.x, lo.y, lo.z, lo.w, hi.x, hi.y, hi.z, hi.w};
#pragma unroll
    for (int j = 0; j < 8; ++j) {
        const short h = bf16_rn(f[j]);
        p0[j] = h;
        p1[j] = bf16_rn(f[j] - bf16_f(h));
    }
}

// ---- Kernel 0: pre-split W into fragment-layout bf16 planes (256 KB) ------
// wpl[g*512 + (c*2+p)*64 + l] = plane_p( W[c*16 + (l&15)][g*32 + (l>>4)*8 .. +8] )
__global__ void prep_w(const float* __restrict__ W, bf16x8* __restrict__ wpl) {
    const int g = blockIdx.x;          // 0..31 (K window of 32)
    const int c = threadIdx.x >> 6;    // 0..3
    const int l = threadIdx.x & 63;
    const int e  = c * 16 + (l & 15);
    const int k0 = g * 32 + (l >> 4) * 8;
    const float4 lo = *(const float4*)(W + (long)e * D + k0);
    const float4 hi = *(const float4*)(W + (long)e * D + k0 + 4);
    bf16x8 p0, p1; split2(lo, hi, p0, p1);
    const int base = ((g * 4 + c) * 2) * 64 + l;
    wpl[base]      = p0;
    wpl[base + 64] = p1;
}

// ---- Kernel 1: zero-barrier register-pipelined bf16-split MFMA router -----
// 1024 blocks x 256 thr (4 waves, independent). Wave = 32 tokens x 64 experts.
// A: 2-step raw-register pipeline (loads at s split at s+2 -> ~900cyc cover).
// W: prep_w fragment planes from global (8KB/step, L1-broadcast).
// No LDS, no __syncthreads -> no vmcnt(0) barrier drains.
__global__ __launch_bounds__(256, 4)
void router_mfma(const float* __restrict__ x, const bf16x8* __restrict__ wpl,
                 float* __restrict__ out, unsigned* __restrict__ wcnt,
                 unsigned* __restrict__ wlist, unsigned cap)
{
    const int tid = threadIdx.x;
    const int wv  = tid >> 6;
    const int l   = tid & 63;
    const int lg  = l >> 4;       // k-octet
    const int lr  = l & 15;       // token row in tile / expert in ctile
    const long t0 = (long)blockIdx.x * 128 + wv * 32;

    f32x4 acc[2][4];
#pragma unroll
    for (int a = 0; a < 2; ++a)
#pragma unroll
        for (int c = 0; c < 4; ++c) acc[a][c] = f32x4{0.f, 0.f, 0.f, 0.f};

    const float* xr0 = x + (t0 + lr) * (long)D + lg * 8;
    const float* xr1 = xr0 + 16 * (long)D;

    float4 rawA[2][2], rawB[2][2];   // [tile][lo/hi] raw fp32 A
    bf16x8 afr[2][2];                // [tile][plane] current-step A planes

#define LOADA(dst, S)                                              \
    dst[0][0] = *(const float4*)(xr0 + (S) * 32);                  \
    dst[0][1] = *(const float4*)(xr0 + (S) * 32 + 4);              \
    dst[1][0] = *(const float4*)(xr1 + (S) * 32);                  \
    dst[1][1] = *(const float4*)(xr1 + (S) * 32 + 4);

    // One K-step: split raw (A(g)), reuse raw regs for A(g+2) issue, MFMA.
#define STEP(g, raw)                                               \
    {                                                              \
        split2(raw[0][0], raw[0][1], afr[0][0], afr[0][1]);        \
        split2(raw[1][0], raw[1][1], afr[1][0], afr[1][1]);        \
        if ((g) + 2 < NSTEPS) { LOADA(raw, (g) + 2) }              \
        _Pragma("unroll")                                          \
        for (int c = 0; c < 4; ++c) {                              \
            const bf16x8 b0 = wpl[(size_t)(g) * 512 + (c * 2 + 0) * 64 + l]; \
            const bf16x8 b1 = wpl[(size_t)(g) * 512 + (c * 2 + 1) * 64 + l]; \
            _Pragma("unroll")                                      \
            for (int a = 0; a < 2; ++a) {                          \
                acc[a][c] = __builtin_amdgcn_mfma_f32_16x16x32_bf16(afr[a][0], b0, acc[a][c], 0, 0, 0); \
                acc[a][c] = __builtin_amdgcn_mfma_f32_16x16x32_bf16(afr[a][1], b0, acc[a][c], 0, 0, 0); \
                acc[a][c] = __builtin_amdgcn_mfma_f32_16x16x32_bf16(afr[a][0], b1, acc[a][c], 0, 0, 0); \
            }                                                      \
        }                                                          \
    }

    // prologue: A(0) -> rawA, A(1) -> rawB
    LOADA(rawA, 0)
    LOADA(rawB, 1)

#pragma unroll 1
    for (int sp = 0; sp < NSTEPS / 2; ++sp) {
        STEP(2 * sp,     rawA)
        STEP(2 * sp + 1, rawB)
    }
#undef STEP
#undef LOADA

    // ---- epilogue: top-3 per token, provisional write + gap-flag ----
    // C/D: col = lane&15 (expert in ctile), row = (lane>>4)*4 + reg (token)
#pragma unroll
    for (int a = 0; a < 2; ++a)
#pragma unroll
    for (int r = 0; r < 4; ++r) {
        float v1 = acc[a][0][r]; int i1 = lr;
        float v2 = -INFINITY;    int i2 = 1 << 20;
        float v3 = -INFINITY;
#pragma unroll
        for (int c = 1; c < 4; ++c) {
            const float v = acc[a][c][r]; const int e = lr + 16 * c;
            if (v > v1)      { v3 = v2; v2 = v1; i2 = i1; v1 = v; i1 = e; }
            else if (v > v2) { v3 = v2; v2 = v;  i2 = e; }
            else if (v > v3) { v3 = v; }
        }
#pragma unroll
        for (int m = 8; m >= 1; m >>= 1) {
            const float ov1 = __shfl_xor(v1, m);
            const int   oi1 = __shfl_xor(i1, m);
            const float ov2 = __shfl_xor(v2, m);
            const int   oi2 = __shfl_xor(i2, m);
            const float ov3 = __shfl_xor(v3, m);
            const bool tv = v1 >= ov1;
            const float x2 = tv ? v2 : ov2, x3 = tv ? v3 : ov3;
            const float y1 = tv ? ov1 : v1, y2 = tv ? ov2 : v2;
            const float nv3 = (x2 >= y1) ? fmaxf(x3, y1) : fmaxf(x2, y2);
            const bool aw = (ov1 > v1) || (ov1 == v1 && oi1 < i1);
            const float nv1 = aw ? ov1 : v1; const int ni1 = aw ? oi1 : i1;
            const float c1v = aw ? v1  : ov1; const int c1i = aw ? i1  : oi1;
            const float c2v = aw ? ov2 : v2;  const int c2i = aw ? oi2 : i2;
            const bool bw = (c1v > c2v) || (c1v == c2v && c1i < c2i);
            v1 = nv1; i1 = ni1;
            v2 = bw ? c1v : c2v; i2 = bw ? c1i : c2i;
            v3 = nv3;
        }
        if (lr == 0) {
            const long t = t0 + a * 16 + lg * 4 + r;
            const float e  = expf(v2 - v1);
            const float dn = 1.0f + e;
            out[t * 2 + 0] = (float)i1;
            out[t * 2 + 1] = (float)i2;
            out[(long)T_TOKENS * 2 + t * 2 + 0] = 1.0f / dn;
            out[(long)T_TOKENS * 2 + t * 2 + 1] = e / dn;
            if (v1 - v2 < EPS_GAP || v2 - v3 < EPS_GAP) {
                const unsigned p = atomicAdd(wcnt, 1u);
                if (p < cap) wlist[p] = (unsigned)t;
            }
        }
    }
}

// ---- Kernel 2: exact-chain fixup, 4 waves/token (one per OpenBLAS panel) --
// Exact OpenBLAS-SKYLAKEX chain (verified R7+): panels 320/320/192/192,
// ascending-k fp32 FMA chain per panel, sequential rounded folds.
__global__ __launch_bounds__(256)
void router_fixup(const float* __restrict__ x, const float* __restrict__ W,
                  float* __restrict__ out, const unsigned* __restrict__ wcnt,
                  const unsigned* __restrict__ wlist, unsigned cap)
{
    __shared__ float ps[4][64];
    unsigned cnt = wcnt[0]; if (cnt > cap) cnt = cap;
    const int wv = threadIdx.x >> 6;   // panel id
    const int l  = threadIdx.x & 63;   // expert
    const int kb = (wv == 0) ? 0 : (wv == 1) ? 320 : (wv == 2) ? 640 : 832;
    const int ke = (wv == 0) ? 320 : (wv == 1) ? 640 : (wv == 2) ? 832 : 1024;

    for (unsigned it = blockIdx.x; it < cnt; it += gridDim.x) {
        const long t = (long)wlist[it];
        const float* xr = x + t * (long)D;
        const float* wr = W + (long)l * D;
        float accP = 0.f;
#pragma unroll 4
        for (int k = kb; k < ke; k += 4) {
            const float4 xv = *(const float4*)(xr + k);
            const float4 wvv = *(const float4*)(wr + k);
            accP = fmaf(xv.x, wvv.x, accP);
            accP = fmaf(xv.y, wvv.y, accP);
            accP = fmaf(xv.z, wvv.z, accP);
            accP = fmaf(xv.w, wvv.w, accP);
        }
        ps[wv][l] = accP;
        __syncthreads();
        if (wv == 0) {
            const float accT = __fadd_rn(__fadd_rn(__fadd_rn(ps[0][l], ps[1][l]), ps[2][l]), ps[3][l]);
            float v1 = accT; int i1 = l;
            float v2 = -INFINITY; int i2 = 1 << 20;
#pragma unroll
            for (int m = 32; m >= 1; m >>= 1) {
                const float ov1 = __shfl_xor(v1, m);
                const int   oi1 = __shfl_xor(i1, m);
                const float ov2 = __shfl_xor(v2, m);
                const int   oi2 = __shfl_xor(i2, m);
                const bool aw = (ov1 > v1) || (ov1 == v1 && oi1 < i1);
                const float nv1 = aw ? ov1 : v1; const int ni1 = aw ? oi1 : i1;
                const float c1v = aw ? v1  : ov1; const int c1i = aw ? i1  : oi1;
                const float c2v = aw ? ov2 : v2;  const int c2i = aw ? oi2 : i2;
                const bool bw = (c1v > c2v) || (c1v == c2v && c1i < c2i);
                v1 = nv1; i1 = ni1;
                v2 = bw ? c1v : c2v; i2 = bw ? c1i : c2i;
            }
            if (l == 0) {
                const float e  = expf(v2 - v1);
                const float dn = 1.0f + e;
                out[t * 2 + 0] = (float)i1;
                out[t * 2 + 1] = (float)i2;
                out[(long)T_TOKENS * 2 + t * 2 + 0] = 1.0f / dn;
                out[(long)T_TOKENS * 2 + t * 2 + 1] = e / dn;
            }
        }
        __syncthreads();
    }
}

extern "C" void kernel_launch(void* const* d_in, const int* in_sizes, int n_in,
                              void* d_out, int out_size, void* d_ws, size_t ws_size,
                              hipStream_t stream) {
    const float* x = (const float*)d_in[0];
    const float* W = (const float*)d_in[1];
    float* out = (float*)d_out;

    // workspace layout: [0,64) wcnt | [1024, 1024+256K) W frag planes | wlist
    unsigned* wcnt  = (unsigned*)d_ws;
    bf16x8*   wpl   = (bf16x8*)((char*)d_ws + 1024);
    unsigned* wlist = (unsigned*)((char*)d_ws + 1024 + 262144);
    size_t rem = (ws_size - 1024 - 262144) / 4;
    unsigned cap = (unsigned)(rem > (1u << 22) ? (1u << 22) : rem);

    (void)hipMemsetAsync(d_ws, 0, 64, stream);
    prep_w<<<dim3(32), dim3(256), 0, stream>>>(W, wpl);
    router_mfma<<<dim3(T_TOKENS / 128), dim3(256), 0, stream>>>(x, wpl, out, wcnt, wlist, cap);
    router_fixup<<<dim3(512), dim3(256), 0, stream>>>(x, W, out, wcnt, wlist, cap);
}

// Round 15
// 208.948 us; speedup vs baseline: 1.2162x; 1.0027x over previous
//
#include <hip/hip_runtime.h>
#include <math.h>

// Problem constants: T=131072, D_IN=1024, NE=64, top_k=2
constexpr int T_TOKENS = 131072;
constexpr int D        = 1024;
constexpr int NSTEPS   = 32;       // K steps of 32
constexpr float EPS_GAP = 1e-3f;   // flag threshold (bf16-split err ~1e-5 RMS)

typedef __attribute__((ext_vector_type(8))) short bf16x8;
typedef __attribute__((ext_vector_type(4))) float f32x4;
typedef __bf16 bf16v8 __attribute__((ext_vector_type(8)));
typedef float  f32v8  __attribute__((ext_vector_type(8)));

// split 8 fp32 into two bf16 planes via HW v_cvt_pk_bf16_f32 (RNE):
// f ~= p0 + p1. __builtin_convertvector lowers to packed cvt on gfx950.
__device__ __forceinline__ void split2(const float4 lo, const float4 hi,
                                       bf16x8& p0, bf16x8& p1) {
    f32v8 f = {lo.x, lo.y, lo.z, lo.w, hi.x, hi.y, hi.z, hi.w};
    bf16v8 h0 = __builtin_convertvector(f, bf16v8);
    f32v8 back = __builtin_convertvector(h0, f32v8);
    bf16v8 h1 = __builtin_convertvector(f - back, bf16v8);
    p0 = __builtin_bit_cast(bf16x8, h0);
    p1 = __builtin_bit_cast(bf16x8, h1);
}

// ---- Kernel 0: pre-split W into fragment-layout bf16 planes (256 KB) ------
// wpl[g*512 + (c*2+p)*64 + l] = plane_p( W[c*16 + (l&15)][g*32 + (l>>4)*8 .. +8] )
__global__ void prep_w(const float* __restrict__ W, bf16x8* __restrict__ wpl) {
    const int g = blockIdx.x;          // 0..31 (K window of 32)
    const int c = threadIdx.x >> 6;    // 0..3
    const int l = threadIdx.x & 63;
    const int e  = c * 16 + (l & 15);
    const int k0 = g * 32 + (l >> 4) * 8;
    const float4 lo = *(const float4*)(W + (long)e * D + k0);
    const float4 hi = *(const float4*)(W + (long)e * D + k0 + 4);
    bf16x8 p0, p1; split2(lo, hi, p0, p1);
    const int base = ((g * 4 + c) * 2) * 64 + l;
    wpl[base]      = p0;
    wpl[base + 64] = p1;
}

// ---- Kernel 1: zero-barrier register-pipelined bf16-split MFMA router -----
// 1024 blocks x 256 thr (4 waves, independent). Wave = 32 tokens x 64 experts.
// A: 2-step raw-register pipeline (loads at s split at s+2 -> ~900cyc cover).
// W: prep_w fragment planes from global (8KB/step, L1-broadcast).
// No LDS, no __syncthreads -> no vmcnt(0) barrier drains.
__global__ __launch_bounds__(256, 4)
void router_mfma(const float* __restrict__ x, const bf16x8* __restrict__ wpl,
                 float* __restrict__ out, unsigned* __restrict__ wcnt,
                 unsigned* __restrict__ wlist, unsigned cap)
{
    const int tid = threadIdx.x;
    const int wv  = tid >> 6;
    const int l   = tid & 63;
    const int lg  = l >> 4;       // k-octet
    const int lr  = l & 15;       // token row in tile / expert in ctile
    const long t0 = (long)blockIdx.x * 128 + wv * 32;

    f32x4 acc[2][4];
#pragma unroll
    for (int a = 0; a < 2; ++a)
#pragma unroll
        for (int c = 0; c < 4; ++c) acc[a][c] = f32x4{0.f, 0.f, 0.f, 0.f};

    const float* xr0 = x + (t0 + lr) * (long)D + lg * 8;
    const float* xr1 = xr0 + 16 * (long)D;

    float4 rawA[2][2], rawB[2][2];   // [tile][lo/hi] raw fp32 A
    bf16x8 afr[2][2];                // [tile][plane] current-step A planes

#define LOADA(dst, S)                                              \
    dst[0][0] = *(const float4*)(xr0 + (S) * 32);                  \
    dst[0][1] = *(const float4*)(xr0 + (S) * 32 + 4);              \
    dst[1][0] = *(const float4*)(xr1 + (S) * 32);                  \
    dst[1][1] = *(const float4*)(xr1 + (S) * 32 + 4);

    // One K-step: split raw (A(g)), reuse raw regs for A(g+2) issue, MFMA.
#define STEP(g, raw)                                               \
    {                                                              \
        split2(raw[0][0], raw[0][1], afr[0][0], afr[0][1]);        \
        split2(raw[1][0], raw[1][1], afr[1][0], afr[1][1]);        \
        if ((g) + 2 < NSTEPS) { LOADA(raw, (g) + 2) }              \
        _Pragma("unroll")                                          \
        for (int c = 0; c < 4; ++c) {                              \
            const bf16x8 b0 = wpl[(size_t)(g) * 512 + (c * 2 + 0) * 64 + l]; \
            const bf16x8 b1 = wpl[(size_t)(g) * 512 + (c * 2 + 1) * 64 + l]; \
            _Pragma("unroll")                                      \
            for (int a = 0; a < 2; ++a) {                          \
                acc[a][c] = __builtin_amdgcn_mfma_f32_16x16x32_bf16(afr[a][0], b0, acc[a][c], 0, 0, 0); \
                acc[a][c] = __builtin_amdgcn_mfma_f32_16x16x32_bf16(afr[a][1], b0, acc[a][c], 0, 0, 0); \
                acc[a][c] = __builtin_amdgcn_mfma_f32_16x16x32_bf16(afr[a][0], b1, acc[a][c], 0, 0, 0); \
            }                                                      \
        }                                                          \
    }

    // prologue: A(0) -> rawA, A(1) -> rawB
    LOADA(rawA, 0)
    LOADA(rawB, 1)

#pragma unroll 1
    for (int sp = 0; sp < NSTEPS / 2; ++sp) {
        STEP(2 * sp,     rawA)
        STEP(2 * sp + 1, rawB)
    }
#undef STEP
#undef LOADA

    // ---- epilogue: top-3 per token, provisional write + gap-flag ----
    // C/D: col = lane&15 (expert in ctile), row = (lane>>4)*4 + reg (token)
#pragma unroll
    for (int a = 0; a < 2; ++a)
#pragma unroll
    for (int r = 0; r < 4; ++r) {
        float v1 = acc[a][0][r]; int i1 = lr;
        float v2 = -INFINITY;    int i2 = 1 << 20;
        float v3 = -INFINITY;
#pragma unroll
        for (int c = 1; c < 4; ++c) {
            const float v = acc[a][c][r]; const int e = lr + 16 * c;
            if (v > v1)      { v3 = v2; v2 = v1; i2 = i1; v1 = v; i1 = e; }
            else if (v > v2) { v3 = v2; v2 = v;  i2 = e; }
            else if (v > v3) { v3 = v; }
        }
#pragma unroll
        for (int m = 8; m >= 1; m >>= 1) {
            const float ov1 = __shfl_xor(v1, m);
            const int   oi1 = __shfl_xor(i1, m);
            const float ov2 = __shfl_xor(v2, m);
            const int   oi2 = __shfl_xor(i2, m);
            const float ov3 = __shfl_xor(v3, m);
            const bool tv = v1 >= ov1;
            const float x2 = tv ? v2 : ov2, x3 = tv ? v3 : ov3;
            const float y1 = tv ? ov1 : v1, y2 = tv ? ov2 : v2;
            const float nv3 = (x2 >= y1) ? fmaxf(x3, y1) : fmaxf(x2, y2);
            const bool aw = (ov1 > v1) || (ov1 == v1 && oi1 < i1);
            const float nv1 = aw ? ov1 : v1; const int ni1 = aw ? oi1 : i1;
            const float c1v = aw ? v1  : ov1; const int c1i = aw ? i1  : oi1;
            const float c2v = aw ? ov2 : v2;  const int c2i = aw ? oi2 : i2;
            const bool bw = (c1v > c2v) || (c1v == c2v && c1i < c2i);
            v1 = nv1; i1 = ni1;
            v2 = bw ? c1v : c2v; i2 = bw ? c1i : c2i;
            v3 = nv3;
        }
        if (lr == 0) {
            const long t = t0 + a * 16 + lg * 4 + r;
            const float e  = expf(v2 - v1);
            const float dn = 1.0f + e;
            out[t * 2 + 0] = (float)i1;
            out[t * 2 + 1] = (float)i2;
            out[(long)T_TOKENS * 2 + t * 2 + 0] = 1.0f / dn;
            out[(long)T_TOKENS * 2 + t * 2 + 1] = e / dn;
            if (v1 - v2 < EPS_GAP || v2 - v3 < EPS_GAP) {
                const unsigned p = atomicAdd(wcnt, 1u);
                if (p < cap) wlist[p] = (unsigned)t;
            }
        }
    }
}

// ---- Kernel 2: exact-chain fixup, 4 waves/token (one per OpenBLAS panel) --
// Exact OpenBLAS-SKYLAKEX chain (verified R7+): panels 320/320/192/192,
// ascending-k fp32 FMA chain per panel, sequential rounded folds.
__global__ __launch_bounds__(256)
void router_fixup(const float* __restrict__ x, const float* __restrict__ W,
                  float* __restrict__ out, const unsigned* __restrict__ wcnt,
                  const unsigned* __restrict__ wlist, unsigned cap)
{
    __shared__ float ps[4][64];
    unsigned cnt = wcnt[0]; if (cnt > cap) cnt = cap;
    const int wv = threadIdx.x >> 6;   // panel id
    const int l  = threadIdx.x & 63;   // expert
    const int kb = (wv == 0) ? 0 : (wv == 1) ? 320 : (wv == 2) ? 640 : 832;
    const int ke = (wv == 0) ? 320 : (wv == 1) ? 640 : (wv == 2) ? 832 : 1024;

    for (unsigned it = blockIdx.x; it < cnt; it += gridDim.x) {
        const long t = (long)wlist[it];
        const float* xr = x + t * (long)D;
        const float* wr = W + (long)l * D;
        float accP = 0.f;
#pragma unroll 4
        for (int k = kb; k < ke; k += 4) {
            const float4 xv = *(const float4*)(xr + k);
            const float4 wvv = *(const float4*)(wr + k);
            accP = fmaf(xv.x, wvv.x, accP);
            accP = fmaf(xv.y, wvv.y, accP);
            accP = fmaf(xv.z, wvv.z, accP);
            accP = fmaf(xv.w, wvv.w, accP);
        }
        ps[wv][l] = accP;
        __syncthreads();
        if (wv == 0) {
            const float accT = __fadd_rn(__fadd_rn(__fadd_rn(ps[0][l], ps[1][l]), ps[2][l]), ps[3][l]);
            float v1 = accT; int i1 = l;
            float v2 = -INFINITY; int i2 = 1 << 20;
#pragma unroll
            for (int m = 32; m >= 1; m >>= 1) {
                const float ov1 = __shfl_xor(v1, m);
                const int   oi1 = __shfl_xor(i1, m);
                const float ov2 = __shfl_xor(v2, m);
                const int   oi2 = __shfl_xor(i2, m);
                const bool aw = (ov1 > v1) || (ov1 == v1 && oi1 < i1);
                const float nv1 = aw ? ov1 : v1; const int ni1 = aw ? oi1 : i1;
                const float c1v = aw ? v1  : ov1; const int c1i = aw ? i1  : oi1;
                const float c2v = aw ? ov2 : v2;  const int c2i = aw ? oi2 : i2;
                const bool bw = (c1v > c2v) || (c1v == c2v && c1i < c2i);
                v1 = nv1; i1 = ni1;
                v2 = bw ? c1v : c2v; i2 = bw ? c1i : c2i;
            }
            if (l == 0) {
                const float e  = expf(v2 - v1);
                const float dn = 1.0f + e;
                out[t * 2 + 0] = (float)i1;
                out[t * 2 + 1] = (float)i2;
                out[(long)T_TOKENS * 2 + t * 2 + 0] = 1.0f / dn;
                out[(long)T_TOKENS * 2 + t * 2 + 1] = e / dn;
            }
        }
        __syncthreads();
    }
}

extern "C" void kernel_launch(void* const* d_in, const int* in_sizes, int n_in,
                              void* d_out, int out_size, void* d_ws, size_t ws_size,
                              hipStream_t stream) {
    const float* x = (const float*)d_in[0];
    const float* W = (const float*)d_in[1];
    float* out = (float*)d_out;

    // workspace layout: [0,64) wcnt | [1024, 1024+256K) W frag planes | wlist
    unsigned* wcnt  = (unsigned*)d_ws;
    bf16x8*   wpl   = (bf16x8*)((char*)d_ws + 1024);
    unsigned* wlist = (unsigned*)((char*)d_ws + 1024 + 262144);
    size_t rem = (ws_size - 1024 - 262144) / 4;
    unsigned cap = (unsigned)(rem > (1u << 22) ? (1u << 22) : rem);

    (void)hipMemsetAsync(d_ws, 0, 64, stream);
    prep_w<<<dim3(32), dim3(256), 0, stream>>>(W, wpl);
    router_mfma<<<dim3(T_TOKENS / 128), dim3(256), 0, stream>>>(x, wpl, out, wcnt, wlist, cap);
    router_fixup<<<dim3(512), dim3(256), 0, stream>>>(x, W, out, wcnt, wlist, cap);
}

// Round 16
// 191.439 us; speedup vs baseline: 1.3274x; 1.0915x over previous
//
#include <hip/hip_runtime.h>
#include <math.h>

// Problem constants: T=131072, D_IN=1024, NE=64, top_k=2
constexpr int T_TOKENS = 131072;
constexpr int D        = 1024;
constexpr float EPS_GAP = 1e-3f;   // flag threshold (bf16-split err ~1e-5 RMS)

typedef __attribute__((ext_vector_type(8))) short bf16x8;
typedef __attribute__((ext_vector_type(4))) float f32x4;
typedef __bf16 bf16v8 __attribute__((ext_vector_type(8)));
typedef float  f32v8  __attribute__((ext_vector_type(8)));

// split 8 fp32 into two bf16 planes (RNE): f ~= p0 + p1
__device__ __forceinline__ void split2(const float4 lo, const float4 hi,
                                       bf16x8& p0, bf16x8& p1) {
    f32v8 f = {lo.x, lo.y, lo.z, lo.w, hi.x, hi.y, hi.z, hi.w};
    bf16v8 h0 = __builtin_convertvector(f, bf16v8);
    f32v8 back = __builtin_convertvector(h0, f32v8);
    bf16v8 h1 = __builtin_convertvector(f - back, bf16v8);
    p0 = __builtin_bit_cast(bf16x8, h0);
    p1 = __builtin_bit_cast(bf16x8, h1);
}

// ---- Kernel 0: pre-split W into fragment-layout bf16 planes (256 KB) ------
// wpl[g*512 + (c*2+p)*64 + l] = plane_p( W[c*16 + (l&15)][g*32 + (l>>4)*8 .. +8] )
__global__ void prep_w(const float* __restrict__ W, bf16x8* __restrict__ wpl) {
    const int g = blockIdx.x;          // 0..31 (K window of 32)
    const int c = threadIdx.x >> 6;    // 0..3
    const int l = threadIdx.x & 63;
    const int e  = c * 16 + (l & 15);
    const int k0 = g * 32 + (l >> 4) * 8;
    const float4 lo = *(const float4*)(W + (long)e * D + k0);
    const float4 hi = *(const float4*)(W + (long)e * D + k0 + 4);
    bf16x8 p0, p1; split2(lo, hi, p0, p1);
    const int base = ((g * 4 + c) * 2) * 64 + l;
    wpl[base]      = p0;
    wpl[base + 64] = p1;
}

// ---- Kernel 1: wave-private LDS-staged MFMA router, counted-vmcnt sync ----
// 1024 blocks x 256 thr (4 waves, fully independent; NO __syncthreads).
// Wave = 32 tokens x 64 experts. A: 256B-contiguous-per-row chunks (KSTEP=64)
// staged via global_load_lds into wave-private double buffers; sync via
// s_waitcnt vmcnt(24) only (stage(s+1) stays in flight across compute).
// W: prep_w fragment planes, loads hoisted to iteration top so their
// compiler waits (vmcnt(8)) never drain the staging pipeline.
__global__ __launch_bounds__(256, 2)
void router_mfma(const float* __restrict__ x, const bf16x8* __restrict__ wpl,
                 float* __restrict__ out, unsigned* __restrict__ wcnt,
                 unsigned* __restrict__ wlist, unsigned cap)
{
    __shared__ __align__(16) char Xs[4][2][8192];   // [wave][buf][32 rows x 256B]

    const int tid = threadIdx.x;
    const int wv  = tid >> 6;
    const int l   = tid & 63;
    const int lg  = l >> 4;       // k-octet
    const int lr  = l & 15;       // token row in tile / expert in ctile
    const long t0 = (long)blockIdx.x * 128 + wv * 32;
    const int swz = (lr & 7) << 4;

    f32x4 acc[2][4];
#pragma unroll
    for (int a = 0; a < 2; ++a)
#pragma unroll
        for (int c = 0; c < 4; ++c) acc[a][c] = f32x4{0.f, 0.f, 0.f, 0.f};

    // staging geometry: instruction i covers rows 4i..4i+3; lane covers
    // bytes [(l&15)*16, +16) of row (4i + (l>>4))'s 256B chunk window.
    const int sil = (l & 15) * 16;
    const int sir = l >> 4;
    const char* xb = (const char*)x;

#define STAGE(S, BUF)                                                          \
    {                                                                          \
        _Pragma("unroll")                                                      \
        for (int i = 0; i < 8; ++i) {                                          \
            const int rr = 4 * i + sir;                                        \
            const char* src = xb + (t0 + rr) * 4096L + (S) * 256               \
                              + (sil ^ ((rr & 7) << 4));                       \
            char* dst = &Xs[wv][BUF][i * 1024];                                \
            __builtin_amdgcn_global_load_lds(                                  \
                (const __attribute__((address_space(1))) void*)src,            \
                (__attribute__((address_space(3))) void*)dst, 16, 0, 0);       \
        }                                                                      \
    }

#define SUBSTEP(SUB, W)                                                        \
    {                                                                          \
        const int c0 = (SUB) * 128 + lg * 32;                                  \
        const float4 lo0 = *(const float4*)(wb + lr * 256 + ((c0) ^ swz));     \
        const float4 hi0 = *(const float4*)(wb + lr * 256 + ((c0 + 16) ^ swz));\
        const float4 lo1 = *(const float4*)(wb + (16 + lr) * 256 + ((c0) ^ swz));     \
        const float4 hi1 = *(const float4*)(wb + (16 + lr) * 256 + ((c0 + 16) ^ swz));\
        bf16x8 a00, a01, a10, a11;                                             \
        split2(lo0, hi0, a00, a01);                                            \
        split2(lo1, hi1, a10, a11);                                            \
        _Pragma("unroll")                                                      \
        for (int c = 0; c < 4; ++c) {                                          \
            acc[0][c] = __builtin_amdgcn_mfma_f32_16x16x32_bf16(a00, W[c*2+0], acc[0][c], 0, 0, 0); \
            acc[0][c] = __builtin_amdgcn_mfma_f32_16x16x32_bf16(a01, W[c*2+0], acc[0][c], 0, 0, 0); \
            acc[0][c] = __builtin_amdgcn_mfma_f32_16x16x32_bf16(a00, W[c*2+1], acc[0][c], 0, 0, 0); \
            acc[1][c] = __builtin_amdgcn_mfma_f32_16x16x32_bf16(a10, W[c*2+0], acc[1][c], 0, 0, 0); \
            acc[1][c] = __builtin_amdgcn_mfma_f32_16x16x32_bf16(a11, W[c*2+0], acc[1][c], 0, 0, 0); \
            acc[1][c] = __builtin_amdgcn_mfma_f32_16x16x32_bf16(a10, W[c*2+1], acc[1][c], 0, 0, 0); \
        }                                                                      \
    }

    STAGE(0, 0);

#pragma unroll 1
    for (int s = 0; s < 16; ++s) {
        const int buf = s & 1;
        // 1. W prefetch for substeps (g = 2s, 2s+1) -- BEFORE stage issue
        bf16x8 w0[8], w1[8];
#pragma unroll
        for (int c = 0; c < 4; ++c) {
            w0[c * 2 + 0] = wpl[(size_t)(2 * s) * 512 + (c * 2 + 0) * 64 + l];
            w0[c * 2 + 1] = wpl[(size_t)(2 * s) * 512 + (c * 2 + 1) * 64 + l];
            w1[c * 2 + 0] = wpl[(size_t)(2 * s + 1) * 512 + (c * 2 + 0) * 64 + l];
            w1[c * 2 + 1] = wpl[(size_t)(2 * s + 1) * 512 + (c * 2 + 1) * 64 + l];
        }
        // 2. issue next chunk's staging (clamped last iter; redundant, unread)
        const int sn = (s + 1 < 16) ? s + 1 : 15;
        if (buf) { STAGE(sn, 0) } else { STAGE(sn, 1) }
        // 3. chunk s staged?  outstanding <= W(16) + stage_next(8) = 24
        asm volatile("s_waitcnt vmcnt(24)" ::: "memory");
        __builtin_amdgcn_sched_barrier(0);
        // 4. compute chunk s (2 substeps of 32 k)
        const char* wb = &Xs[wv][buf][0];
        SUBSTEP(0, w0)
        SUBSTEP(1, w1)
    }
#undef SUBSTEP
#undef STAGE

    // ---- epilogue: top-3 per token, provisional write + gap-flag ----
    // C/D: col = lane&15 (expert in ctile), row = (lane>>4)*4 + reg (token)
#pragma unroll
    for (int a = 0; a < 2; ++a)
#pragma unroll
    for (int r = 0; r < 4; ++r) {
        float v1 = acc[a][0][r]; int i1 = lr;
        float v2 = -INFINITY;    int i2 = 1 << 20;
        float v3 = -INFINITY;
#pragma unroll
        for (int c = 1; c < 4; ++c) {
            const float v = acc[a][c][r]; const int e = lr + 16 * c;
            if (v > v1)      { v3 = v2; v2 = v1; i2 = i1; v1 = v; i1 = e; }
            else if (v > v2) { v3 = v2; v2 = v;  i2 = e; }
            else if (v > v3) { v3 = v; }
        }
#pragma unroll
        for (int m = 8; m >= 1; m >>= 1) {
            const float ov1 = __shfl_xor(v1, m);
            const int   oi1 = __shfl_xor(i1, m);
            const float ov2 = __shfl_xor(v2, m);
            const int   oi2 = __shfl_xor(i2, m);
            const float ov3 = __shfl_xor(v3, m);
            const bool tv = v1 >= ov1;
            const float x2 = tv ? v2 : ov2, x3 = tv ? v3 : ov3;
            const float y1 = tv ? ov1 : v1, y2 = tv ? ov2 : v2;
            const float nv3 = (x2 >= y1) ? fmaxf(x3, y1) : fmaxf(x2, y2);
            const bool aw = (ov1 > v1) || (ov1 == v1 && oi1 < i1);
            const float nv1 = aw ? ov1 : v1; const int ni1 = aw ? oi1 : i1;
            const float c1v = aw ? v1  : ov1; const int c1i = aw ? i1  : oi1;
            const float c2v = aw ? ov2 : v2;  const int c2i = aw ? oi2 : i2;
            const bool bw = (c1v > c2v) || (c1v == c2v && c1i < c2i);
            v1 = nv1; i1 = ni1;
            v2 = bw ? c1v : c2v; i2 = bw ? c1i : c2i;
            v3 = nv3;
        }
        if (lr == 0) {
            const long t = t0 + a * 16 + lg * 4 + r;
            const float e  = expf(v2 - v1);
            const float dn = 1.0f + e;
            out[t * 2 + 0] = (float)i1;
            out[t * 2 + 1] = (float)i2;
            out[(long)T_TOKENS * 2 + t * 2 + 0] = 1.0f / dn;
            out[(long)T_TOKENS * 2 + t * 2 + 1] = e / dn;
            if (v1 - v2 < EPS_GAP || v2 - v3 < EPS_GAP) {
                const unsigned p = atomicAdd(wcnt, 1u);
                if (p < cap) wlist[p] = (unsigned)t;
            }
        }
    }
}

// ---- Kernel 2: exact-chain fixup, 4 waves/token (one per OpenBLAS panel) --
// Exact OpenBLAS-SKYLAKEX chain (verified R7+): panels 320/320/192/192,
// ascending-k fp32 FMA chain per panel, sequential rounded folds.
__global__ __launch_bounds__(256)
void router_fixup(const float* __restrict__ x, const float* __restrict__ W,
                  float* __restrict__ out, const unsigned* __restrict__ wcnt,
                  const unsigned* __restrict__ wlist, unsigned cap)
{
    __shared__ float ps[4][64];
    unsigned cnt = wcnt[0]; if (cnt > cap) cnt = cap;
    const int wv = threadIdx.x >> 6;   // panel id
    const int l  = threadIdx.x & 63;   // expert
    const int kb = (wv == 0) ? 0 : (wv == 1) ? 320 : (wv == 2) ? 640 : 832;
    const int ke = (wv == 0) ? 320 : (wv == 1) ? 640 : (wv == 2) ? 832 : 1024;

    for (unsigned it = blockIdx.x; it < cnt; it += gridDim.x) {
        const long t = (long)wlist[it];
        const float* xr = x + t * (long)D;
        const float* wr = W + (long)l * D;
        float accP = 0.f;
#pragma unroll 4
        for (int k = kb; k < ke; k += 4) {
            const float4 xv = *(const float4*)(xr + k);
            const float4 wvv = *(const float4*)(wr + k);
            accP = fmaf(xv.x, wvv.x, accP);
            accP = fmaf(xv.y, wvv.y, accP);
            accP = fmaf(xv.z, wvv.z, accP);
            accP = fmaf(xv.w, wvv.w, accP);
        }
        ps[wv][l] = accP;
        __syncthreads();
        if (wv == 0) {
            const float accT = __fadd_rn(__fadd_rn(__fadd_rn(ps[0][l], ps[1][l]), ps[2][l]), ps[3][l]);
            float v1 = accT; int i1 = l;
            float v2 = -INFINITY; int i2 = 1 << 20;
#pragma unroll
            for (int m = 32; m >= 1; m >>= 1) {
                const float ov1 = __shfl_xor(v1, m);
                const int   oi1 = __shfl_xor(i1, m);
                const float ov2 = __shfl_xor(v2, m);
                const int   oi2 = __shfl_xor(i2, m);
                const bool aw = (ov1 > v1) || (ov1 == v1 && oi1 < i1);
                const float nv1 = aw ? ov1 : v1; const int ni1 = aw ? oi1 : i1;
                const float c1v = aw ? v1  : ov1; const int c1i = aw ? i1  : oi1;
                const float c2v = aw ? ov2 : v2;  const int c2i = aw ? oi2 : i2;
                const bool bw = (c1v > c2v) || (c1v == c2v && c1i < c2i);
                v1 = nv1; i1 = ni1;
                v2 = bw ? c1v : c2v; i2 = bw ? c1i : c2i;
            }
            if (l == 0) {
                const float e  = expf(v2 - v1);
                const float dn = 1.0f + e;
                out[t * 2 + 0] = (float)i1;
                out[t * 2 + 1] = (float)i2;
                out[(long)T_TOKENS * 2 + t * 2 + 0] = 1.0f / dn;
                out[(long)T_TOKENS * 2 + t * 2 + 1] = e / dn;
            }
        }
        __syncthreads();
    }
}

extern "C" void kernel_launch(void* const* d_in, const int* in_sizes, int n_in,
                              void* d_out, int out_size, void* d_ws, size_t ws_size,
                              hipStream_t stream) {
    const float* x = (const float*)d_in[0];
    const float* W = (const float*)d_in[1];
    float* out = (float*)d_out;

    // workspace layout: [0,64) wcnt | [1024, 1024+256K) W frag planes | wlist
    unsigned* wcnt  = (unsigned*)d_ws;
    bf16x8*   wpl   = (bf16x8*)((char*)d_ws + 1024);
    unsigned* wlist = (unsigned*)((char*)d_ws + 1024 + 262144);
    size_t rem = (ws_size - 1024 - 262144) / 4;
    unsigned cap = (unsigned)(rem > (1u << 22) ? (1u << 22) : rem);

    (void)hipMemsetAsync(d_ws, 0, 64, stream);
    prep_w<<<dim3(32), dim3(256), 0, stream>>>(W, wpl);
    router_mfma<<<dim3(T_TOKENS / 128), dim3(256), 0, stream>>>(x, wpl, out, wcnt, wlist, cap);
    router_fixup<<<dim3(512), dim3(256), 0, stream>>>(x, W, out, wcnt, wlist, cap);
}